// Round 1
// baseline (1099.740 us; speedup 1.0000x reference)
//
#include <hip/hip_runtime.h>
#include <math.h>

#define NGENES 50000
#define NEDGES 5000
#define NNZ_C 1600000
#define NPATH 500
#define DIM 128
#define BB 64
#define MM 200

// ---------------- wave helpers ----------------
__device__ inline float wred_sum(float x) {
#pragma unroll
  for (int off = 32; off > 0; off >>= 1) x += __shfl_down(x, off, 64);
  return x;  // lane 0 holds sum
}
__device__ inline float wred_max(float x) {
#pragma unroll
  for (int off = 32; off > 0; off >>= 1) x = fmaxf(x, __shfl_down(x, off, 64));
  return x;
}
__device__ inline int wave_incl_scan(int x) {
  int lane = threadIdx.x & 63;
#pragma unroll
  for (int off = 1; off < 64; off <<= 1) {
    int y = __shfl_up(x, off, 64);
    if (lane >= off) x += y;
  }
  return x;
}

// ---------------- build kernels ----------------
__global__ void k_hist(const int* __restrict__ rows, const int* __restrict__ cols,
                       const float* __restrict__ vals,
                       float* __restrict__ Dv, float* __restrict__ De,
                       int* __restrict__ row_cnt, int* __restrict__ col_cnt) {
  int i = blockIdx.x * blockDim.x + threadIdx.x;
  if (i >= NNZ_C) return;
  int r = rows[i], c = cols[i];
  float v = vals[i];
  atomicAdd(Dv + r, v);
  atomicAdd(De + c, v);
  atomicAdd(row_cnt + r, 1);
  atomicAdd(col_cnt + c, 1);
}

// single-block exclusive scan (blockDim = 1024)
__global__ void k_scan_excl(const int* __restrict__ in, int* __restrict__ out, int n) {
  __shared__ int wsum[16];
  __shared__ int carry_s;
  int tid = threadIdx.x, lane = tid & 63, wid = tid >> 6;
  if (tid == 0) carry_s = 0;
  __syncthreads();
  for (int base = 0; base < n; base += 1024) {
    int i = base + tid;
    int x = (i < n) ? in[i] : 0;
    int incl = wave_incl_scan(x);
    if (lane == 63) wsum[wid] = incl;
    __syncthreads();
    int woff = 0;
    for (int w = 0; w < wid; ++w) woff += wsum[w];
    int carry = carry_s;
    if (i < n) out[i] = carry + woff + incl - x;
    __syncthreads();
    if (tid == 1023) carry_s = carry + woff + incl;
    __syncthreads();
  }
}

__global__ void k_place(const int* __restrict__ rows, const int* __restrict__ cols,
                        const float* __restrict__ vals, const float* __restrict__ Dv,
                        const int* __restrict__ col_start, int* __restrict__ col_cur,
                        const int* __restrict__ row_start, int* __restrict__ row_cur,
                        int* __restrict__ csc_row, float* __restrict__ csc_w,
                        int* __restrict__ csr_col, float* __restrict__ csr_val) {
  int i = blockIdx.x * blockDim.x + threadIdx.x;
  if (i >= NNZ_C) return;
  int r = rows[i], c = cols[i];
  float v = vals[i];
  float w = v / sqrtf(Dv[r] + 1e-6f);  // v * dv[r]
  int p1 = col_start[c] + atomicAdd(col_cur + c, 1);
  csc_row[p1] = r;
  csc_w[p1] = w;
  int p2 = row_start[r] + atomicAdd(row_cur + r, 1);
  csr_col[p2] = c;
  csr_val[p2] = v;
}

// pass B: HXde[e,:] = (1/(De[e]+1e-6)) * sum_i w_i * gene_embed[r_i,:]
__global__ void k_edge(const int* __restrict__ col_start, const int* __restrict__ col_cnt,
                       const int* __restrict__ csc_row, const float* __restrict__ csc_w,
                       const float* __restrict__ gene_embed, const float* __restrict__ De,
                       float* __restrict__ HXde) {
  int e = blockIdx.x;
  int d = threadIdx.x;
  int s = col_start[e], n = col_cnt[e];
  float acc = 0.f;
  int i = s;
  int end = s + n;
  for (; i + 4 <= end; i += 4) {
    int r0 = csc_row[i], r1 = csc_row[i + 1], r2 = csc_row[i + 2], r3 = csc_row[i + 3];
    float w0 = csc_w[i], w1 = csc_w[i + 1], w2 = csc_w[i + 2], w3 = csc_w[i + 3];
    float x0 = gene_embed[(size_t)r0 * DIM + d];
    float x1 = gene_embed[(size_t)r1 * DIM + d];
    float x2 = gene_embed[(size_t)r2 * DIM + d];
    float x3 = gene_embed[(size_t)r3 * DIM + d];
    acc += w0 * x0;
    acc += w1 * x1;
    acc += w2 * x2;
    acc += w3 * x3;
  }
  for (; i < end; ++i) acc += csc_w[i] * gene_embed[(size_t)csc_row[i] * DIM + d];
  HXde[e * DIM + d] = acc / (De[e] + 1e-6f);
}

// pass C fused with gene_ids gather: Xg[bm,:] = dv[g] * sum_i v_i * HXde[c_i,:]
__global__ void k_gene(const int* __restrict__ gene_ids, const int* __restrict__ row_start,
                       const int* __restrict__ row_cnt, const int* __restrict__ csr_col,
                       const float* __restrict__ csr_val, const float* __restrict__ HXde,
                       const float* __restrict__ Dv, float* __restrict__ Xg) {
  int bm = blockIdx.x;
  int d = threadIdx.x;
  int g = gene_ids[bm];
  int s = row_start[g], n = row_cnt[g];
  float acc = 0.f;
  int i = s, end = s + n;
  for (; i + 4 <= end; i += 4) {
    int c0 = csr_col[i], c1 = csr_col[i + 1], c2 = csr_col[i + 2], c3 = csr_col[i + 3];
    float v0 = csr_val[i], v1 = csr_val[i + 1], v2 = csr_val[i + 2], v3 = csr_val[i + 3];
    acc += v0 * HXde[c0 * DIM + d];
    acc += v1 * HXde[c1 * DIM + d];
    acc += v2 * HXde[c2 * DIM + d];
    acc += v3 * HXde[c3 * DIM + d];
  }
  for (; i < end; ++i) acc += csr_val[i] * HXde[csr_col[i] * DIM + d];
  float dvg = 1.f / sqrtf(Dv[g] + 1e-6f);
  Xg[(size_t)bm * DIM + d] = acc * dvg;
}

// rep[b,p,d] = (sum_m Xg[b,m,d]*mask[m,p]) / max(cnt[p],1)
#define PT 20
__global__ void k_pathway(const int* __restrict__ gene_ids,
                          const float* __restrict__ gene_pathway,
                          const float* __restrict__ Xg, float* __restrict__ rep) {
  int b = blockIdx.y;
  int p0 = blockIdx.x * PT;
  int d = threadIdx.x;
  float acc[PT], cnt[PT];
#pragma unroll
  for (int pp = 0; pp < PT; ++pp) { acc[pp] = 0.f; cnt[pp] = 0.f; }
  for (int m = 0; m < MM; ++m) {
    int g = gene_ids[b * MM + m];
    float x = Xg[(size_t)(b * MM + m) * DIM + d];
    const float* mrow = gene_pathway + (size_t)g * NPATH + p0;
#pragma unroll
    for (int pp = 0; pp < PT; ++pp) {
      float mv = mrow[pp];
      acc[pp] += mv * x;
      cnt[pp] += mv;
    }
  }
#pragma unroll
  for (int pp = 0; pp < PT; ++pp) {
    rep[((size_t)b * NPATH + p0 + pp) * DIM + d] = acc[pp] / fmaxf(cnt[pp], 1.f);
  }
}

// scores[b,p] = tanh([rep,ctx] @ W1 + b1) @ W2 + b2
#define PT2 10
__global__ void k_attn(const float* __restrict__ rep, const float* __restrict__ treatment_embed,
                       const int* __restrict__ context_ids, const float* __restrict__ W1,
                       const float* __restrict__ b1, const float* __restrict__ W2,
                       const float* __restrict__ b2, float* __restrict__ scores) {
  __shared__ float in_s[PT2][2 * DIM];
  __shared__ float part[PT2][2];
  int b = blockIdx.y;
  int p0 = blockIdx.x * PT2;
  int j = threadIdx.x;
  int lane = j & 63, wid = j >> 6;
  int ctx_id = context_ids[b];
  float ctxv = treatment_embed[ctx_id * DIM + j];
#pragma unroll
  for (int pp = 0; pp < PT2; ++pp) {
    in_s[pp][j] = rep[((size_t)b * NPATH + p0 + pp) * DIM + j];
    in_s[pp][DIM + j] = ctxv;
  }
  __syncthreads();
  float b1j = b1[j];
  float acc[PT2];
#pragma unroll
  for (int pp = 0; pp < PT2; ++pp) acc[pp] = b1j;
  for (int k = 0; k < 2 * DIM; ++k) {
    float w1 = W1[k * DIM + j];
#pragma unroll
    for (int pp = 0; pp < PT2; ++pp) acc[pp] += in_s[pp][k] * w1;
  }
  float w2 = W2[j];
#pragma unroll
  for (int pp = 0; pp < PT2; ++pp) {
    float t = tanhf(acc[pp]) * w2;
    t = wred_sum(t);
    if (lane == 0) part[pp][wid] = t;
  }
  __syncthreads();
  if (j < PT2) scores[b * NPATH + p0 + j] = part[j][0] + part[j][1] + b2[0];
}

// softmax + z0 + z + risk, one block per b (128 threads)
__global__ void k_final(const float* __restrict__ scores, const float* __restrict__ rep,
                        const float* __restrict__ latent_W, const float* __restrict__ latent_b,
                        const float* __restrict__ risk_W, const float* __restrict__ risk_b,
                        float* __restrict__ out) {
  __shared__ float w_s[NPATH];
  __shared__ float z0_s[DIM];
  __shared__ float red_max[2], red_sum[2], red_risk[2];
  int b = blockIdx.x, t = threadIdx.x;
  int lane = t & 63, wid = t >> 6;
  float lmax = -3.4e38f;
  for (int p = t; p < NPATH; p += 128) {
    float s = scores[b * NPATH + p];
    w_s[p] = s;
    lmax = fmaxf(lmax, s);
  }
  lmax = wred_max(lmax);
  if (lane == 0) red_max[wid] = lmax;
  __syncthreads();
  float bmax = fmaxf(red_max[0], red_max[1]);
  float lsum = 0.f;
  for (int p = t; p < NPATH; p += 128) {
    float e = expf(w_s[p] - bmax);
    w_s[p] = e;
    lsum += e;
  }
  lsum = wred_sum(lsum);
  if (lane == 0) red_sum[wid] = lsum;
  __syncthreads();
  float inv = 1.f / (red_sum[0] + red_sum[1]);
  // z0[d] = (sum_p e_p * rep[b,p,d]) * inv
  float z0 = 0.f;
  int d = t;
  for (int p = 0; p < NPATH; ++p) z0 += w_s[p] * rep[((size_t)b * NPATH + p) * DIM + d];
  z0 *= inv;
  z0_s[d] = z0;
  __syncthreads();
  float z = latent_b[t];
  for (int dd = 0; dd < DIM; ++dd) z += z0_s[dd] * latent_W[dd * DIM + t];
  out[BB + b * DIM + t] = z;
  float r = z * risk_W[t];
  r = wred_sum(r);
  if (lane == 0) red_risk[wid] = r;
  __syncthreads();
  if (t == 0) out[b] = red_risk[0] + red_risk[1] + risk_b[0];
}

extern "C" void kernel_launch(void* const* d_in, const int* in_sizes, int n_in,
                              void* d_out, int out_size, void* d_ws, size_t ws_size,
                              hipStream_t stream) {
  const int* gene_ids = (const int*)d_in[0];
  const int* context_ids = (const int*)d_in[1];
  const int* H_rows = (const int*)d_in[2];
  const int* H_cols = (const int*)d_in[3];
  const float* H_vals = (const float*)d_in[4];
  const float* gene_embed = (const float*)d_in[5];
  const float* treatment_embed = (const float*)d_in[6];
  const float* gene_pathway = (const float*)d_in[7];
  const float* W1 = (const float*)d_in[8];
  const float* b1 = (const float*)d_in[9];
  const float* W2 = (const float*)d_in[10];
  const float* b2 = (const float*)d_in[11];
  const float* latent_W = (const float*)d_in[12];
  const float* latent_b = (const float*)d_in[13];
  const float* risk_W = (const float*)d_in[14];
  const float* risk_b = (const float*)d_in[15];
  float* out = (float*)d_out;

  char* ws = (char*)d_ws;
  float* Dv = (float*)(ws + 0);            // 50000
  float* De = (float*)(ws + 200000);       // 5000
  int* col_cnt = (int*)(ws + 220000);      // 5000
  int* col_cur = (int*)(ws + 240000);      // 5000
  int* row_cnt = (int*)(ws + 260000);      // 50000
  int* row_cur = (int*)(ws + 460000);      // 50000
  int* col_start = (int*)(ws + 660000);    // 5000
  int* row_start = (int*)(ws + 680000);    // 50000
  int* csc_row = (int*)(ws + 880000);      // NNZ
  float* csc_w = (float*)(ws + 7280000);   // NNZ
  int* csr_col = (int*)(ws + 13680000);    // NNZ
  float* csr_val = (float*)(ws + 20080000);// NNZ
  float* HXde = (float*)(ws + 26480000);   // 5000*128
  float* Xg = (float*)(ws + 29040000);     // 64*200*128
  float* rep = (float*)(ws + 35593600);    // 64*500*128
  float* scores = (float*)(ws + 51977600); // 64*500

  // zero Dv, De, col_cnt, col_cur, row_cnt, row_cur (contiguous 660000 B)
  hipMemsetAsync(d_ws, 0, 660000, stream);

  int nb = (NNZ_C + 255) / 256;
  k_hist<<<nb, 256, 0, stream>>>(H_rows, H_cols, H_vals, Dv, De, row_cnt, col_cnt);
  k_scan_excl<<<1, 1024, 0, stream>>>(col_cnt, col_start, NEDGES);
  k_scan_excl<<<1, 1024, 0, stream>>>(row_cnt, row_start, NGENES);
  k_place<<<nb, 256, 0, stream>>>(H_rows, H_cols, H_vals, Dv, col_start, col_cur,
                                  row_start, row_cur, csc_row, csc_w, csr_col, csr_val);
  k_edge<<<NEDGES, DIM, 0, stream>>>(col_start, col_cnt, csc_row, csc_w, gene_embed, De, HXde);
  k_gene<<<BB * MM, DIM, 0, stream>>>(gene_ids, row_start, row_cnt, csr_col, csr_val, HXde, Dv, Xg);
  k_pathway<<<dim3(NPATH / PT, BB), DIM, 0, stream>>>(gene_ids, gene_pathway, Xg, rep);
  k_attn<<<dim3(NPATH / PT2, BB), DIM, 0, stream>>>(rep, treatment_embed, context_ids, W1, b1,
                                                    W2, b2, scores);
  k_final<<<BB, DIM, 0, stream>>>(scores, rep, latent_W, latent_b, risk_W, risk_b, out);
}

// Round 2
// 707.369 us; speedup vs baseline: 1.5547x; 1.5547x over previous
//
#include <hip/hip_runtime.h>
#include <math.h>

#define NGENES 50000
#define NEDGES 5000
#define NNZ_C 1600000
#define NPATH 500
#define DIM 128
#define BB 64
#define MM 200
#define BMN (BB * MM)
#define NBMW 1568          // bitmap words (50176 bits >= 50000)
#define CSRCAP 768000      // expected marked CSR entries ~410K

// ---------------- wave helpers ----------------
__device__ inline float wred_sum(float x) {
#pragma unroll
  for (int off = 32; off > 0; off >>= 1) x += __shfl_down(x, off, 64);
  return x;
}
__device__ inline float wred_max(float x) {
#pragma unroll
  for (int off = 32; off > 0; off >>= 1) x = fmaxf(x, __shfl_down(x, off, 64));
  return x;
}
__device__ inline int wave_incl_scan(int x) {
  int lane = threadIdx.x & 63;
#pragma unroll
  for (int off = 1; off < 64; off <<= 1) {
    int y = __shfl_up(x, off, 64);
    if (lane >= off) x += y;
  }
  return x;
}

// mark genes referenced by gene_ids in a bitmap
__global__ void k_mark(const int* __restrict__ gene_ids, unsigned* __restrict__ bitmap) {
  int i = blockIdx.x * blockDim.x + threadIdx.x;
  if (i >= BMN) return;
  int g = gene_ids[i];
  atomicOr(bitmap + (g >> 5), 1u << (g & 31));
}

// histograms: col-side (cnt + val-sum) in LDS then merged; row-side Dv global atomics,
// row_cnt only for marked genes.
__global__ void k_hist(const int* __restrict__ rows, const int* __restrict__ cols,
                       const float* __restrict__ vals, const unsigned* __restrict__ bitmap,
                       float* __restrict__ Dv, float* __restrict__ De,
                       int* __restrict__ row_cnt, int* __restrict__ col_cnt) {
  __shared__ int ccnt[NEDGES];
  __shared__ float csum[NEDGES];
  __shared__ unsigned bm_s[NBMW];
  int tid = threadIdx.x;
  for (int i = tid; i < NEDGES; i += 256) { ccnt[i] = 0; csum[i] = 0.f; }
  for (int i = tid; i < NBMW; i += 256) bm_s[i] = bitmap[i];
  __syncthreads();
  int stride = gridDim.x * 256;
  for (int i = blockIdx.x * 256 + tid; i < NNZ_C; i += stride) {
    int r = rows[i], c = cols[i];
    float v = vals[i];
    atomicAdd(Dv + r, v);
    if ((bm_s[r >> 5] >> (r & 31)) & 1) atomicAdd(row_cnt + r, 1);
    atomicAdd(&ccnt[c], 1);
    atomicAdd(&csum[c], v);
  }
  __syncthreads();
  for (int c = tid; c < NEDGES; c += 256) {
    int n = ccnt[c];
    if (n) {
      atomicAdd(col_cnt + c, n);
      atomicAdd(De + c, csum[c]);
    }
  }
}

// single-block exclusive scan (blockDim = 1024)
__global__ void k_scan_excl(const int* __restrict__ in, int* __restrict__ out, int n) {
  __shared__ int wsum[16];
  __shared__ int carry_s;
  int tid = threadIdx.x, lane = tid & 63, wid = tid >> 6;
  if (tid == 0) carry_s = 0;
  __syncthreads();
  for (int base = 0; base < n; base += 1024) {
    int i = base + tid;
    int x = (i < n) ? in[i] : 0;
    int incl = wave_incl_scan(x);
    if (lane == 63) wsum[wid] = incl;
    __syncthreads();
    int woff = 0;
    for (int w = 0; w < wid; ++w) woff += wsum[w];
    int carry = carry_s;
    if (i < n) out[i] = carry + woff + incl - x;
    __syncthreads();
    if (tid == 1023) carry_s = carry + woff + incl;
    __syncthreads();
  }
}

// placement: CSC via two-phase LDS reservation; CSR only for marked rows. Packed int2 entries.
__global__ void k_place(const int* __restrict__ rows, const int* __restrict__ cols,
                        const float* __restrict__ vals, const float* __restrict__ Dv,
                        const int* __restrict__ col_start, int* __restrict__ col_cur,
                        const int* __restrict__ row_start, int* __restrict__ row_cur,
                        const unsigned* __restrict__ bitmap,
                        int2* __restrict__ csc, int2* __restrict__ csr) {
  __shared__ int cnt_s[NEDGES];
  __shared__ int base_s[NEDGES];
  __shared__ unsigned bm_s[NBMW];
  int tid = threadIdx.x;
  for (int i = tid; i < NEDGES; i += 256) cnt_s[i] = 0;
  for (int i = tid; i < NBMW; i += 256) bm_s[i] = bitmap[i];
  __syncthreads();
  const int chunk = (NNZ_C + gridDim.x - 1) / gridDim.x;
  int lo = blockIdx.x * chunk;
  int hi = min(lo + chunk, NNZ_C);
  for (int i = lo + tid; i < hi; i += 256) atomicAdd(&cnt_s[cols[i]], 1);
  __syncthreads();
  for (int c = tid; c < NEDGES; c += 256) {
    int n = cnt_s[c];
    if (n) {
      base_s[c] = col_start[c] + atomicAdd(col_cur + c, n);
      cnt_s[c] = 0;
    }
  }
  __syncthreads();
  for (int i = lo + tid; i < hi; i += 256) {
    int r = rows[i], c = cols[i];
    float v = vals[i];
    float w = v / sqrtf(Dv[r] + 1e-6f);
    int pos = base_s[c] + atomicAdd(&cnt_s[c], 1);
    csc[pos] = make_int2(r, __float_as_int(w));
    if ((bm_s[r >> 5] >> (r & 31)) & 1) {
      int p2 = row_start[r] + atomicAdd(row_cur + r, 1);
      if (p2 < CSRCAP) csr[p2] = make_int2(c, __float_as_int(v));
    }
  }
}

// pass B: HXde[e,:] = (1/(De[e]+1e-6)) * sum_i w_i * gene_embed[r_i,:]
// block = 128 threads = 4 groups of 32 lanes; each group one entry at a time, float4 per lane
__global__ void k_edge(const int* __restrict__ col_start, const int2* __restrict__ csc,
                       const float* __restrict__ gene_embed, const float* __restrict__ De,
                       float* __restrict__ HXde) {
  __shared__ float4 red[4][32];
  int e = blockIdx.x;
  int s = col_start[e];
  int end = (e == NEDGES - 1) ? NNZ_C : col_start[e + 1];
  int g = threadIdx.x >> 5, l = threadIdx.x & 31;
  float4 acc = make_float4(0.f, 0.f, 0.f, 0.f);
  for (int i = s + g; i < end; i += 4) {
    int2 ent = csc[i];
    float w = __int_as_float(ent.y);
    float4 x = *((const float4*)(gene_embed + (size_t)ent.x * DIM) + l);
    acc.x += w * x.x; acc.y += w * x.y; acc.z += w * x.z; acc.w += w * x.w;
  }
  red[g][l] = acc;
  __syncthreads();
  if (g == 0) {
    float4 a = red[0][l], b = red[1][l], c = red[2][l], d = red[3][l];
    float inv = 1.f / (De[e] + 1e-6f);
    float4 o;
    o.x = (a.x + b.x + c.x + d.x) * inv;
    o.y = (a.y + b.y + c.y + d.y) * inv;
    o.z = (a.z + b.z + c.z + d.z) * inv;
    o.w = (a.w + b.w + c.w + d.w) * inv;
    *((float4*)(HXde + (size_t)e * DIM) + l) = o;
  }
}

// pass C fused with gene_ids gather (partial CSR)
__global__ void k_gene(const int* __restrict__ gene_ids, const int* __restrict__ row_start,
                       const int* __restrict__ row_cnt, const int2* __restrict__ csr,
                       const float* __restrict__ HXde, const float* __restrict__ Dv,
                       float* __restrict__ Xg) {
  __shared__ float4 red[4][32];
  int bm = blockIdx.x;
  int gene = gene_ids[bm];
  int s = row_start[gene], n = row_cnt[gene];
  int g = threadIdx.x >> 5, l = threadIdx.x & 31;
  float4 acc = make_float4(0.f, 0.f, 0.f, 0.f);
  for (int i = s + g; i < s + n; i += 4) {
    int2 ent = csr[i];
    float v = __int_as_float(ent.y);
    float4 x = *((const float4*)(HXde + (size_t)ent.x * DIM) + l);
    acc.x += v * x.x; acc.y += v * x.y; acc.z += v * x.z; acc.w += v * x.w;
  }
  red[g][l] = acc;
  __syncthreads();
  if (g == 0) {
    float4 a = red[0][l], b = red[1][l], c = red[2][l], d = red[3][l];
    float dvg = 1.f / sqrtf(Dv[gene] + 1e-6f);
    float4 o;
    o.x = (a.x + b.x + c.x + d.x) * dvg;
    o.y = (a.y + b.y + c.y + d.y) * dvg;
    o.z = (a.z + b.z + c.z + d.z) * dvg;
    o.w = (a.w + b.w + c.w + d.w) * dvg;
    *((float4*)(Xg + (size_t)bm * DIM) + l) = o;
  }
}

// rep[b,p,d] = (sum_m Xg[b,m,d]*mask[m,p]) / max(cnt[p],1)
#define PT 20
__global__ void k_pathway(const int* __restrict__ gene_ids,
                          const float* __restrict__ gene_pathway,
                          const float* __restrict__ Xg, float* __restrict__ rep) {
  int b = blockIdx.y;
  int p0 = blockIdx.x * PT;
  int d = threadIdx.x;
  float acc[PT], cnt[PT];
#pragma unroll
  for (int pp = 0; pp < PT; ++pp) { acc[pp] = 0.f; cnt[pp] = 0.f; }
  for (int m = 0; m < MM; ++m) {
    int g = gene_ids[b * MM + m];
    float x = Xg[(size_t)(b * MM + m) * DIM + d];
    const float* mrow = gene_pathway + (size_t)g * NPATH + p0;
#pragma unroll
    for (int pp = 0; pp < PT; ++pp) {
      float mv = mrow[pp];
      acc[pp] += mv * x;
      cnt[pp] += mv;
    }
  }
#pragma unroll
  for (int pp = 0; pp < PT; ++pp) {
    rep[((size_t)b * NPATH + p0 + pp) * DIM + d] = acc[pp] / fmaxf(cnt[pp], 1.f);
  }
}

// ctxW[b,j] = sum_k ctx[b,k] * W1[D+k, j]   (per-b part of the attention MLP)
__global__ void k_ctxw(const int* __restrict__ context_ids,
                       const float* __restrict__ treatment_embed,
                       const float* __restrict__ W1, float* __restrict__ ctxW) {
  __shared__ float ctx_s[DIM];
  int b = blockIdx.x, j = threadIdx.x;
  ctx_s[j] = treatment_embed[context_ids[b] * DIM + j];
  __syncthreads();
  float acc = 0.f;
  for (int k = 0; k < DIM; ++k) acc += ctx_s[k] * W1[(DIM + k) * DIM + j];
  ctxW[b * DIM + j] = acc;
}

// scores[b,p] = tanh(rep@W1_top + ctxW + b1) @ W2 + b2
#define PT2 10
__global__ void k_attn(const float* __restrict__ rep, const float* __restrict__ ctxW,
                       const float* __restrict__ W1, const float* __restrict__ b1,
                       const float* __restrict__ W2, const float* __restrict__ b2,
                       float* __restrict__ scores) {
  __shared__ float in_s[PT2][DIM];
  __shared__ float part[PT2][2];
  int b = blockIdx.y;
  int p0 = blockIdx.x * PT2;
  int j = threadIdx.x;
  int lane = j & 63, wid = j >> 6;
#pragma unroll
  for (int pp = 0; pp < PT2; ++pp)
    in_s[pp][j] = rep[((size_t)b * NPATH + p0 + pp) * DIM + j];
  __syncthreads();
  float base = b1[j] + ctxW[b * DIM + j];
  float acc[PT2];
#pragma unroll
  for (int pp = 0; pp < PT2; ++pp) acc[pp] = base;
  for (int k = 0; k < DIM; ++k) {
    float w1 = W1[k * DIM + j];
#pragma unroll
    for (int pp = 0; pp < PT2; ++pp) acc[pp] += in_s[pp][k] * w1;
  }
  float w2 = W2[j];
#pragma unroll
  for (int pp = 0; pp < PT2; ++pp) {
    float t = tanhf(acc[pp]) * w2;
    t = wred_sum(t);
    if (lane == 0) part[pp][wid] = t;
  }
  __syncthreads();
  if (j < PT2) scores[b * NPATH + p0 + j] = part[j][0] + part[j][1] + b2[0];
}

// softmax + z0 + z + risk, one block per b (128 threads)
__global__ void k_final(const float* __restrict__ scores, const float* __restrict__ rep,
                        const float* __restrict__ latent_W, const float* __restrict__ latent_b,
                        const float* __restrict__ risk_W, const float* __restrict__ risk_b,
                        float* __restrict__ out) {
  __shared__ float w_s[NPATH];
  __shared__ float z0_s[DIM];
  __shared__ float red_max[2], red_sum[2], red_risk[2];
  int b = blockIdx.x, t = threadIdx.x;
  int lane = t & 63, wid = t >> 6;
  float lmax = -3.4e38f;
  for (int p = t; p < NPATH; p += 128) {
    float s = scores[b * NPATH + p];
    w_s[p] = s;
    lmax = fmaxf(lmax, s);
  }
  lmax = wred_max(lmax);
  if (lane == 0) red_max[wid] = lmax;
  __syncthreads();
  float bmax = fmaxf(red_max[0], red_max[1]);
  float lsum = 0.f;
  for (int p = t; p < NPATH; p += 128) {
    float e = expf(w_s[p] - bmax);
    w_s[p] = e;
    lsum += e;
  }
  lsum = wred_sum(lsum);
  if (lane == 0) red_sum[wid] = lsum;
  __syncthreads();
  float inv = 1.f / (red_sum[0] + red_sum[1]);
  float z0 = 0.f;
  int d = t;
#pragma unroll 4
  for (int p = 0; p < NPATH; ++p) z0 += w_s[p] * rep[((size_t)b * NPATH + p) * DIM + d];
  z0 *= inv;
  z0_s[d] = z0;
  __syncthreads();
  float z = latent_b[t];
  for (int dd = 0; dd < DIM; ++dd) z += z0_s[dd] * latent_W[dd * DIM + t];
  out[BB + b * DIM + t] = z;
  float r = z * risk_W[t];
  r = wred_sum(r);
  if (lane == 0) red_risk[wid] = r;
  __syncthreads();
  if (t == 0) out[b] = red_risk[0] + red_risk[1] + risk_b[0];
}

extern "C" void kernel_launch(void* const* d_in, const int* in_sizes, int n_in,
                              void* d_out, int out_size, void* d_ws, size_t ws_size,
                              hipStream_t stream) {
  const int* gene_ids = (const int*)d_in[0];
  const int* context_ids = (const int*)d_in[1];
  const int* H_rows = (const int*)d_in[2];
  const int* H_cols = (const int*)d_in[3];
  const float* H_vals = (const float*)d_in[4];
  const float* gene_embed = (const float*)d_in[5];
  const float* treatment_embed = (const float*)d_in[6];
  const float* gene_pathway = (const float*)d_in[7];
  const float* W1 = (const float*)d_in[8];
  const float* b1 = (const float*)d_in[9];
  const float* W2 = (const float*)d_in[10];
  const float* b2 = (const float*)d_in[11];
  const float* latent_W = (const float*)d_in[12];
  const float* latent_b = (const float*)d_in[13];
  const float* risk_W = (const float*)d_in[14];
  const float* risk_b = (const float*)d_in[15];
  float* out = (float*)d_out;

  char* ws = (char*)d_ws;
  float* Dv = (float*)(ws + 0);              // 50000 f
  float* De = (float*)(ws + 200000);         // 5000 f
  int* col_cnt = (int*)(ws + 220000);        // 5000 i
  int* col_cur = (int*)(ws + 240000);        // 5000 i
  int* row_cnt = (int*)(ws + 260000);        // 50000 i
  int* row_cur = (int*)(ws + 460000);        // 50000 i
  unsigned* bitmap = (unsigned*)(ws + 660000); // 1568 u32 -> end 666272
  int* col_start = (int*)(ws + 666272);      // 5000 i -> 686272
  int* row_start = (int*)(ws + 686272);      // 50000 i -> 886272
  int2* csc = (int2*)(ws + 886272);          // 1.6M int2 -> 13686272
  int2* csr = (int2*)(ws + 13686272);        // 768K int2 -> 19830272
  float* HXde = (float*)(ws + 19830272);     // 5000*128 -> 22390272
  float* Xg = (float*)(ws + 22390272);       // 12800*128 -> 28943872
  float* rep = (float*)(ws + 28943872);      // 64*500*128 -> 45327872
  float* scores = (float*)(ws + 45327872);   // 64*500 -> 45455872
  float* ctxW = (float*)(ws + 45455872);     // 64*128 -> 45488640

  hipMemsetAsync(d_ws, 0, 666272, stream);

  k_mark<<<(BMN + 255) / 256, 256, 0, stream>>>(gene_ids, bitmap);
  k_hist<<<128, 256, 0, stream>>>(H_rows, H_cols, H_vals, bitmap, Dv, De, row_cnt, col_cnt);
  k_scan_excl<<<1, 1024, 0, stream>>>(col_cnt, col_start, NEDGES);
  k_scan_excl<<<1, 1024, 0, stream>>>(row_cnt, row_start, NGENES);
  k_place<<<256, 256, 0, stream>>>(H_rows, H_cols, H_vals, Dv, col_start, col_cur,
                                   row_start, row_cur, bitmap, csc, csr);
  k_edge<<<NEDGES, 128, 0, stream>>>(col_start, csc, gene_embed, De, HXde);
  k_gene<<<BMN, 128, 0, stream>>>(gene_ids, row_start, row_cnt, csr, HXde, Dv, Xg);
  k_pathway<<<dim3(NPATH / PT, BB), DIM, 0, stream>>>(gene_ids, gene_pathway, Xg, rep);
  k_ctxw<<<BB, DIM, 0, stream>>>(context_ids, treatment_embed, W1, ctxW);
  k_attn<<<dim3(NPATH / PT2, BB), DIM, 0, stream>>>(rep, ctxW, W1, b1, W2, b2, scores);
  k_final<<<BB, DIM, 0, stream>>>(scores, rep, latent_W, latent_b, risk_W, risk_b, out);
}

// Round 3
// 698.885 us; speedup vs baseline: 1.5736x; 1.0121x over previous
//
#include <hip/hip_runtime.h>
#include <math.h>

#define NGENES 50000
#define NEDGES 5000
#define NNZ_C 1600000
#define NPATH 500
#define DIM 128
#define BB 64
#define MM 200
#define BMN (BB * MM)
#define NBMW 1568          // bitmap words (50176 bits >= 50000)
#define CSRCAP 768000      // expected marked CSR entries ~410K

// ---------------- wave helpers ----------------
__device__ inline float wred_sum(float x) {
#pragma unroll
  for (int off = 32; off > 0; off >>= 1) x += __shfl_down(x, off, 64);
  return x;
}
__device__ inline float wred_max(float x) {
#pragma unroll
  for (int off = 32; off > 0; off >>= 1) x = fmaxf(x, __shfl_down(x, off, 64));
  return x;
}
__device__ inline int wave_incl_scan(int x) {
  int lane = threadIdx.x & 63;
#pragma unroll
  for (int off = 1; off < 64; off <<= 1) {
    int y = __shfl_up(x, off, 64);
    if (lane >= off) x += y;
  }
  return x;
}

// mark genes referenced by gene_ids in a bitmap
__global__ void k_mark(const int* __restrict__ gene_ids, unsigned* __restrict__ bitmap) {
  int i = blockIdx.x * blockDim.x + threadIdx.x;
  if (i >= BMN) return;
  int g = gene_ids[i];
  atomicOr(bitmap + (g >> 5), 1u << (g & 31));
}

// row-side histogram: Dv for all genes, row_cnt only for marked genes.
// Low-contention global atomics (avg 32-way over 50K addrs); full-width grid.
__global__ void k_hist_row(const int* __restrict__ rows, const float* __restrict__ vals,
                           const unsigned* __restrict__ bitmap,
                           float* __restrict__ Dv, int* __restrict__ row_cnt) {
  int i = blockIdx.x * blockDim.x + threadIdx.x;
  int stride = gridDim.x * blockDim.x;
  for (; i < NNZ_C; i += stride) {
    int r = rows[i];
    float v = vals[i];
    atomicAdd(Dv + r, v);
    if ((bitmap[r >> 5] >> (r & 31)) & 1) atomicAdd(row_cnt + r, 1);
  }
}

// col-side histogram (cnt + val-sum) in LDS, merged once per block per nonzero bin.
__global__ void k_hist_col(const int* __restrict__ cols, const float* __restrict__ vals,
                           float* __restrict__ De, int* __restrict__ col_cnt) {
  __shared__ int ccnt[NEDGES];
  __shared__ float csum[NEDGES];
  int tid = threadIdx.x;
  for (int i = tid; i < NEDGES; i += 512) { ccnt[i] = 0; csum[i] = 0.f; }
  __syncthreads();
  int stride = gridDim.x * 512;
  for (int i = blockIdx.x * 512 + tid; i < NNZ_C; i += stride) {
    int c = cols[i];
    float v = vals[i];
    atomicAdd(&ccnt[c], 1);
    atomicAdd(&csum[c], v);
  }
  __syncthreads();
  for (int c = tid; c < NEDGES; c += 512) {
    int n = ccnt[c];
    if (n) {
      atomicAdd(col_cnt + c, n);
      atomicAdd(De + c, csum[c]);
    }
  }
}

// single-block exclusive scan (blockDim = 1024)
__global__ void k_scan_excl(const int* __restrict__ in, int* __restrict__ out, int n) {
  __shared__ int wsum[16];
  __shared__ int carry_s;
  int tid = threadIdx.x, lane = tid & 63, wid = tid >> 6;
  if (tid == 0) carry_s = 0;
  __syncthreads();
  for (int base = 0; base < n; base += 1024) {
    int i = base + tid;
    int x = (i < n) ? in[i] : 0;
    int incl = wave_incl_scan(x);
    if (lane == 63) wsum[wid] = incl;
    __syncthreads();
    int woff = 0;
    for (int w = 0; w < wid; ++w) woff += wsum[w];
    int carry = carry_s;
    if (i < n) out[i] = carry + woff + incl - x;
    __syncthreads();
    if (tid == 1023) carry_s = carry + woff + incl;
    __syncthreads();
  }
}

// placement: CSC via two-phase LDS reservation; CSR only for marked rows. Packed int2.
// 128 blocks x 512 threads: ~575K reserve atomics instead of 1.15M.
__global__ void k_place(const int* __restrict__ rows, const int* __restrict__ cols,
                        const float* __restrict__ vals, const float* __restrict__ Dv,
                        const int* __restrict__ col_start, int* __restrict__ col_cur,
                        const int* __restrict__ row_start, int* __restrict__ row_cur,
                        const unsigned* __restrict__ bitmap,
                        int2* __restrict__ csc, int2* __restrict__ csr) {
  __shared__ int cnt_s[NEDGES];
  __shared__ int base_s[NEDGES];
  __shared__ unsigned bm_s[NBMW];
  int tid = threadIdx.x;
  for (int i = tid; i < NEDGES; i += 512) cnt_s[i] = 0;
  for (int i = tid; i < NBMW; i += 512) bm_s[i] = bitmap[i];
  __syncthreads();
  const int chunk = (NNZ_C + gridDim.x - 1) / gridDim.x;
  int lo = blockIdx.x * chunk;
  int hi = min(lo + chunk, NNZ_C);
  for (int i = lo + tid; i < hi; i += 512) atomicAdd(&cnt_s[cols[i]], 1);
  __syncthreads();
  for (int c = tid; c < NEDGES; c += 512) {
    int n = cnt_s[c];
    if (n) {
      base_s[c] = col_start[c] + atomicAdd(col_cur + c, n);
      cnt_s[c] = 0;
    }
  }
  __syncthreads();
  for (int i = lo + tid; i < hi; i += 512) {
    int r = rows[i], c = cols[i];
    float v = vals[i];
    float w = v / sqrtf(Dv[r] + 1e-6f);
    int pos = base_s[c] + atomicAdd(&cnt_s[c], 1);
    csc[pos] = make_int2(r, __float_as_int(w));
    if ((bm_s[r >> 5] >> (r & 31)) & 1) {
      int p2 = row_start[r] + atomicAdd(row_cur + r, 1);
      if (p2 < CSRCAP) csr[p2] = make_int2(c, __float_as_int(v));
    }
  }
}

// pass B: HXde[e,:] = (1/(De[e]+1e-6)) * sum_i w_i * gene_embed[r_i,:]
// 256 threads = 8 half-wave groups; 4-deep unroll = 32 gathers (16 KB) in flight per block.
__global__ void k_edge(const int* __restrict__ col_start, const int2* __restrict__ csc,
                       const float* __restrict__ gene_embed, const float* __restrict__ De,
                       float* __restrict__ HXde) {
  __shared__ float4 red[8][32];
  int e = blockIdx.x;
  int s = col_start[e];
  int end = (e == NEDGES - 1) ? NNZ_C : col_start[e + 1];
  int g = threadIdx.x >> 5, l = threadIdx.x & 31;
  float4 a0 = make_float4(0.f, 0.f, 0.f, 0.f);
  float4 a1 = make_float4(0.f, 0.f, 0.f, 0.f);
  float4 a2 = make_float4(0.f, 0.f, 0.f, 0.f);
  float4 a3 = make_float4(0.f, 0.f, 0.f, 0.f);
  int i = s + g;
  for (; i + 24 < end; i += 32) {
    int2 e0 = csc[i];
    int2 e1 = csc[i + 8];
    int2 e2 = csc[i + 16];
    int2 e3 = csc[i + 24];
    float4 x0 = *((const float4*)(gene_embed + (size_t)e0.x * DIM) + l);
    float4 x1 = *((const float4*)(gene_embed + (size_t)e1.x * DIM) + l);
    float4 x2 = *((const float4*)(gene_embed + (size_t)e2.x * DIM) + l);
    float4 x3 = *((const float4*)(gene_embed + (size_t)e3.x * DIM) + l);
    float w0 = __int_as_float(e0.y), w1 = __int_as_float(e1.y);
    float w2 = __int_as_float(e2.y), w3 = __int_as_float(e3.y);
    a0.x += w0 * x0.x; a0.y += w0 * x0.y; a0.z += w0 * x0.z; a0.w += w0 * x0.w;
    a1.x += w1 * x1.x; a1.y += w1 * x1.y; a1.z += w1 * x1.z; a1.w += w1 * x1.w;
    a2.x += w2 * x2.x; a2.y += w2 * x2.y; a2.z += w2 * x2.z; a2.w += w2 * x2.w;
    a3.x += w3 * x3.x; a3.y += w3 * x3.y; a3.z += w3 * x3.z; a3.w += w3 * x3.w;
  }
  for (; i < end; i += 8) {
    int2 en = csc[i];
    float w = __int_as_float(en.y);
    float4 x = *((const float4*)(gene_embed + (size_t)en.x * DIM) + l);
    a0.x += w * x.x; a0.y += w * x.y; a0.z += w * x.z; a0.w += w * x.w;
  }
  a0.x += a1.x + a2.x + a3.x;
  a0.y += a1.y + a2.y + a3.y;
  a0.z += a1.z + a2.z + a3.z;
  a0.w += a1.w + a2.w + a3.w;
  red[g][l] = a0;
  __syncthreads();
  if (g == 0) {
    float4 o = red[0][l];
#pragma unroll
    for (int gg = 1; gg < 8; ++gg) {
      float4 t = red[gg][l];
      o.x += t.x; o.y += t.y; o.z += t.z; o.w += t.w;
    }
    float inv = 1.f / (De[e] + 1e-6f);
    o.x *= inv; o.y *= inv; o.z *= inv; o.w *= inv;
    *((float4*)(HXde + (size_t)e * DIM) + l) = o;
  }
}

// pass C fused with gene_ids gather (partial CSR); 4 groups, 2-deep unroll
__global__ void k_gene(const int* __restrict__ gene_ids, const int* __restrict__ row_start,
                       const int* __restrict__ row_cnt, const int2* __restrict__ csr,
                       const float* __restrict__ HXde, const float* __restrict__ Dv,
                       float* __restrict__ Xg) {
  __shared__ float4 red[4][32];
  int bm = blockIdx.x;
  int gene = gene_ids[bm];
  int s = row_start[gene], n = row_cnt[gene];
  int end = s + n;
  int g = threadIdx.x >> 5, l = threadIdx.x & 31;
  float4 a0 = make_float4(0.f, 0.f, 0.f, 0.f);
  float4 a1 = make_float4(0.f, 0.f, 0.f, 0.f);
  int i = s + g;
  for (; i + 4 < end; i += 8) {
    int2 e0 = csr[i];
    int2 e1 = csr[i + 4];
    float4 x0 = *((const float4*)(HXde + (size_t)e0.x * DIM) + l);
    float4 x1 = *((const float4*)(HXde + (size_t)e1.x * DIM) + l);
    float v0 = __int_as_float(e0.y), v1 = __int_as_float(e1.y);
    a0.x += v0 * x0.x; a0.y += v0 * x0.y; a0.z += v0 * x0.z; a0.w += v0 * x0.w;
    a1.x += v1 * x1.x; a1.y += v1 * x1.y; a1.z += v1 * x1.z; a1.w += v1 * x1.w;
  }
  for (; i < end; i += 4) {
    int2 en = csr[i];
    float v = __int_as_float(en.y);
    float4 x = *((const float4*)(HXde + (size_t)en.x * DIM) + l);
    a0.x += v * x.x; a0.y += v * x.y; a0.z += v * x.z; a0.w += v * x.w;
  }
  a0.x += a1.x; a0.y += a1.y; a0.z += a1.z; a0.w += a1.w;
  red[g][l] = a0;
  __syncthreads();
  if (g == 0) {
    float4 a = red[0][l], b = red[1][l], c = red[2][l], d = red[3][l];
    float dvg = 1.f / sqrtf(Dv[gene] + 1e-6f);
    float4 o;
    o.x = (a.x + b.x + c.x + d.x) * dvg;
    o.y = (a.y + b.y + c.y + d.y) * dvg;
    o.z = (a.z + b.z + c.z + d.z) * dvg;
    o.w = (a.w + b.w + c.w + d.w) * dvg;
    *((float4*)(Xg + (size_t)bm * DIM) + l) = o;
  }
}

// rep[b,p,d] = (sum_m Xg[b,m,d]*mask[m,p]) / max(cnt[p],1)
#define PT 20
__global__ void k_pathway(const int* __restrict__ gene_ids,
                          const float* __restrict__ gene_pathway,
                          const float* __restrict__ Xg, float* __restrict__ rep) {
  int b = blockIdx.y;
  int p0 = blockIdx.x * PT;
  int d = threadIdx.x;
  float acc[PT], cnt[PT];
#pragma unroll
  for (int pp = 0; pp < PT; ++pp) { acc[pp] = 0.f; cnt[pp] = 0.f; }
  for (int m = 0; m < MM; ++m) {
    int g = gene_ids[b * MM + m];
    float x = Xg[(size_t)(b * MM + m) * DIM + d];
    const float* mrow = gene_pathway + (size_t)g * NPATH + p0;
#pragma unroll
    for (int pp = 0; pp < PT; ++pp) {
      float mv = mrow[pp];
      acc[pp] += mv * x;
      cnt[pp] += mv;
    }
  }
#pragma unroll
  for (int pp = 0; pp < PT; ++pp) {
    rep[((size_t)b * NPATH + p0 + pp) * DIM + d] = acc[pp] / fmaxf(cnt[pp], 1.f);
  }
}

// ctxW[b,j] = sum_k ctx[b,k] * W1[D+k, j]
__global__ void k_ctxw(const int* __restrict__ context_ids,
                       const float* __restrict__ treatment_embed,
                       const float* __restrict__ W1, float* __restrict__ ctxW) {
  __shared__ float ctx_s[DIM];
  int b = blockIdx.x, j = threadIdx.x;
  ctx_s[j] = treatment_embed[context_ids[b] * DIM + j];
  __syncthreads();
  float acc = 0.f;
  for (int k = 0; k < DIM; ++k) acc += ctx_s[k] * W1[(DIM + k) * DIM + j];
  ctxW[b * DIM + j] = acc;
}

// scores[b,p] = tanh(rep@W1_top + ctxW + b1) @ W2 + b2
#define PT2 10
__global__ void k_attn(const float* __restrict__ rep, const float* __restrict__ ctxW,
                       const float* __restrict__ W1, const float* __restrict__ b1,
                       const float* __restrict__ W2, const float* __restrict__ b2,
                       float* __restrict__ scores) {
  __shared__ float in_s[PT2][DIM];
  __shared__ float part[PT2][2];
  int b = blockIdx.y;
  int p0 = blockIdx.x * PT2;
  int j = threadIdx.x;
  int lane = j & 63, wid = j >> 6;
#pragma unroll
  for (int pp = 0; pp < PT2; ++pp)
    in_s[pp][j] = rep[((size_t)b * NPATH + p0 + pp) * DIM + j];
  __syncthreads();
  float base = b1[j] + ctxW[b * DIM + j];
  float acc[PT2];
#pragma unroll
  for (int pp = 0; pp < PT2; ++pp) acc[pp] = base;
  for (int k = 0; k < DIM; ++k) {
    float w1 = W1[k * DIM + j];
#pragma unroll
    for (int pp = 0; pp < PT2; ++pp) acc[pp] += in_s[pp][k] * w1;
  }
  float w2 = W2[j];
#pragma unroll
  for (int pp = 0; pp < PT2; ++pp) {
    float t = tanhf(acc[pp]) * w2;
    t = wred_sum(t);
    if (lane == 0) part[pp][wid] = t;
  }
  __syncthreads();
  if (j < PT2) scores[b * NPATH + p0 + j] = part[j][0] + part[j][1] + b2[0];
}

// softmax + z0 + z + risk, one block per b (128 threads)
__global__ void k_final(const float* __restrict__ scores, const float* __restrict__ rep,
                        const float* __restrict__ latent_W, const float* __restrict__ latent_b,
                        const float* __restrict__ risk_W, const float* __restrict__ risk_b,
                        float* __restrict__ out) {
  __shared__ float w_s[NPATH];
  __shared__ float z0_s[DIM];
  __shared__ float red_max[2], red_sum[2], red_risk[2];
  int b = blockIdx.x, t = threadIdx.x;
  int lane = t & 63, wid = t >> 6;
  float lmax = -3.4e38f;
  for (int p = t; p < NPATH; p += 128) {
    float s = scores[b * NPATH + p];
    w_s[p] = s;
    lmax = fmaxf(lmax, s);
  }
  lmax = wred_max(lmax);
  if (lane == 0) red_max[wid] = lmax;
  __syncthreads();
  float bmax = fmaxf(red_max[0], red_max[1]);
  float lsum = 0.f;
  for (int p = t; p < NPATH; p += 128) {
    float e = expf(w_s[p] - bmax);
    w_s[p] = e;
    lsum += e;
  }
  lsum = wred_sum(lsum);
  if (lane == 0) red_sum[wid] = lsum;
  __syncthreads();
  float inv = 1.f / (red_sum[0] + red_sum[1]);
  float z0 = 0.f;
  int d = t;
#pragma unroll 4
  for (int p = 0; p < NPATH; ++p) z0 += w_s[p] * rep[((size_t)b * NPATH + p) * DIM + d];
  z0 *= inv;
  z0_s[d] = z0;
  __syncthreads();
  float z = latent_b[t];
  for (int dd = 0; dd < DIM; ++dd) z += z0_s[dd] * latent_W[dd * DIM + t];
  out[BB + b * DIM + t] = z;
  float r = z * risk_W[t];
  r = wred_sum(r);
  if (lane == 0) red_risk[wid] = r;
  __syncthreads();
  if (t == 0) out[b] = red_risk[0] + red_risk[1] + risk_b[0];
}

extern "C" void kernel_launch(void* const* d_in, const int* in_sizes, int n_in,
                              void* d_out, int out_size, void* d_ws, size_t ws_size,
                              hipStream_t stream) {
  const int* gene_ids = (const int*)d_in[0];
  const int* context_ids = (const int*)d_in[1];
  const int* H_rows = (const int*)d_in[2];
  const int* H_cols = (const int*)d_in[3];
  const float* H_vals = (const float*)d_in[4];
  const float* gene_embed = (const float*)d_in[5];
  const float* treatment_embed = (const float*)d_in[6];
  const float* gene_pathway = (const float*)d_in[7];
  const float* W1 = (const float*)d_in[8];
  const float* b1 = (const float*)d_in[9];
  const float* W2 = (const float*)d_in[10];
  const float* b2 = (const float*)d_in[11];
  const float* latent_W = (const float*)d_in[12];
  const float* latent_b = (const float*)d_in[13];
  const float* risk_W = (const float*)d_in[14];
  const float* risk_b = (const float*)d_in[15];
  float* out = (float*)d_out;

  char* ws = (char*)d_ws;
  float* Dv = (float*)(ws + 0);                // 50000 f
  float* De = (float*)(ws + 200000);           // 5000 f
  int* col_cnt = (int*)(ws + 220000);          // 5000 i
  int* col_cur = (int*)(ws + 240000);          // 5000 i
  int* row_cnt = (int*)(ws + 260000);          // 50000 i
  int* row_cur = (int*)(ws + 460000);          // 50000 i
  unsigned* bitmap = (unsigned*)(ws + 660000); // 1568 u32 -> 666272
  int* col_start = (int*)(ws + 666272);        // 5000 i -> 686272
  int* row_start = (int*)(ws + 686272);        // 50000 i -> 886272
  int2* csc = (int2*)(ws + 886272);            // 1.6M int2 -> 13686272
  int2* csr = (int2*)(ws + 13686272);          // 768K int2 -> 19830272
  float* HXde = (float*)(ws + 19830272);       // 5000*128 -> 22390272
  float* Xg = (float*)(ws + 22390272);         // 12800*128 -> 28943872
  float* rep = (float*)(ws + 28943872);        // 64*500*128 -> 45327872
  float* scores = (float*)(ws + 45327872);     // 64*500 -> 45455872
  float* ctxW = (float*)(ws + 45455872);       // 64*128 -> 45488640

  hipMemsetAsync(d_ws, 0, 666272, stream);

  k_mark<<<(BMN + 255) / 256, 256, 0, stream>>>(gene_ids, bitmap);
  k_hist_row<<<1024, 256, 0, stream>>>(H_rows, H_vals, bitmap, Dv, row_cnt);
  k_hist_col<<<128, 512, 0, stream>>>(H_cols, H_vals, De, col_cnt);
  k_scan_excl<<<1, 1024, 0, stream>>>(col_cnt, col_start, NEDGES);
  k_scan_excl<<<1, 1024, 0, stream>>>(row_cnt, row_start, NGENES);
  k_place<<<128, 512, 0, stream>>>(H_rows, H_cols, H_vals, Dv, col_start, col_cur,
                                   row_start, row_cur, bitmap, csc, csr);
  k_edge<<<NEDGES, 256, 0, stream>>>(col_start, csc, gene_embed, De, HXde);
  k_gene<<<BMN, 128, 0, stream>>>(gene_ids, row_start, row_cnt, csr, HXde, Dv, Xg);
  k_pathway<<<dim3(NPATH / PT, BB), DIM, 0, stream>>>(gene_ids, gene_pathway, Xg, rep);
  k_ctxw<<<BB, DIM, 0, stream>>>(context_ids, treatment_embed, W1, ctxW);
  k_attn<<<dim3(NPATH / PT2, BB), DIM, 0, stream>>>(rep, ctxW, W1, b1, W2, b2, scores);
  k_final<<<BB, DIM, 0, stream>>>(scores, rep, latent_W, latent_b, risk_W, risk_b, out);
}